// Round 3
// baseline (455.477 us; speedup 1.0000x reference)
//
#include <hip/hip_runtime.h>

#define N_ENT   50000
#define N_ENT_P 50048
#define NDIM    256
#define BATCH   1024
#define MROWS   2048
#define BM      128
#define BN      128
#define NTILES  391
#define NSTRIP  64
#define NCONV   6256        // N_ENT_P*32/256 convert blocks in k_prep
#define SHIFT   30.0f
#define BSCALE  16.0f
#define INVBSC  0.0625f

typedef __attribute__((ext_vector_type(4))) float f32x4;

__device__ __forceinline__ void async16(const void* g, void* lds) {
  __builtin_amdgcn_global_load_lds(
      (const __attribute__((address_space(1))) unsigned int*)g,
      (__attribute__((address_space(3))) unsigned int*)lds,
      16, 0, 0);
}

// ---- K0: fused [ent_w f32 -> fp8(e4m3, x16) with zero-pad] + [BN stats] ----
__global__ void k_prep(const float* __restrict__ ent_w,
                       const int* __restrict__ facts,
                       const float* __restrict__ rel_w,
                       unsigned char* __restrict__ Wf8,
                       float* __restrict__ stats) {
  int bid = blockIdx.x;
  if (bid < NCONV) {
    int t = bid * 256 + threadIdx.x;          // [0, 50048*32)
    int row = t >> 5, c8 = (t & 31) << 3;
    int2 out;
    if (row < N_ENT) {
      const float4* p = (const float4*)(ent_w + row * NDIM + c8);
      float4 f0 = p[0], f1 = p[1];
      int lo = 0, hi = 0;
      lo = __builtin_amdgcn_cvt_pk_fp8_f32(f0.x * BSCALE, f0.y * BSCALE, lo, false);
      lo = __builtin_amdgcn_cvt_pk_fp8_f32(f0.z * BSCALE, f0.w * BSCALE, lo, true);
      hi = __builtin_amdgcn_cvt_pk_fp8_f32(f1.x * BSCALE, f1.y * BSCALE, hi, false);
      hi = __builtin_amdgcn_cvt_pk_fp8_f32(f1.z * BSCALE, f1.w * BSCALE, hi, true);
      out.x = lo; out.y = hi;
    } else {
      out.x = out.y = 0;
    }
    *(int2*)(Wf8 + row * NDIM + c8) = out;
  } else {
    int sb = bid - NCONV;                      // [0,192)
    int seg = sb >> 6;                         // 0=h, 1=t, 2=r
    int d = threadIdx.x;
    const float* tab = (seg == 2) ? rel_w : ent_w;
    int r0 = (sb & 63) * 16;
    int idxs[16];
#pragma unroll
    for (int i = 0; i < 16; ++i) idxs[i] = facts[(r0 + i) * 3 + seg];
    float s = 0.f, s2 = 0.f;
#pragma unroll
    for (int i = 0; i < 16; ++i) {
      float v = tab[idxs[i] * NDIM + d];
      s += v; s2 += v * v;
    }
    atomicAdd(&stats[(seg * 2 + 0) * NDIM + d], s);
    atomicAdd(&stats[(seg * 2 + 1) * NDIM + d], s2);
  }
}

// ---- K2: BN apply + alpha bilinear -> head/tail vec (fp8) + exact label dots ----
__global__ void k_vectors(const int* __restrict__ facts, const int* __restrict__ arch,
                          const float* __restrict__ ent_w, const float* __restrict__ rel_w,
                          const float* __restrict__ bne_g, const float* __restrict__ bne_b,
                          const float* __restrict__ bnr_g, const float* __restrict__ bnr_b,
                          const float* __restrict__ stats,
                          unsigned char* __restrict__ HVf8, float* __restrict__ zlab) {
  __shared__ float sh_he[256], sh_te[256], sh_re[256], sh_alpha[64], sh_red[16];
  int b = blockIdx.x, d = threadIdx.x;
  int h = facts[b * 3 + 0], t = facts[b * 3 + 1], r = facts[b * 3 + 2];
  const float inv = 1.0f / (float)BATCH;
  float mh = stats[0 * 256 + d] * inv, vh = stats[1 * 256 + d] * inv - mh * mh;
  float mt = stats[2 * 256 + d] * inv, vt = stats[3 * 256 + d] * inv - mt * mt;
  float mr = stats[4 * 256 + d] * inv, vr = stats[5 * 256 + d] * inv - mr * mr;
  float sch = rsqrtf(vh + 1e-5f) * bne_g[d], shh = bne_b[d] - mh * sch;
  float sct = rsqrtf(vt + 1e-5f) * bne_g[d], sht = bne_b[d] - mt * sct;
  float scr = rsqrtf(vr + 1e-5f) * bnr_g[d], shr = bnr_b[d] - mr * scr;
  sh_he[d] = ent_w[h * NDIM + d] * sch + shh;
  sh_te[d] = ent_w[t * NDIM + d] * sct + sht;
  sh_re[d] = rel_w[r * NDIM + d] * scr + shr;
  if (d < 64) {
    int a = arch[d];
    sh_alpha[d] = (a == 0) ? 0.f : ((a == 1) ? 1.f : -1.f);
  }
  __syncthreads();
  int k = d >> 6, l = d & 63;
  float hv = 0.f, tv = 0.f;
#pragma unroll
  for (int i = 0; i < 4; ++i) {
    float re_i = sh_re[i * 64 + l];
#pragma unroll
    for (int j = 0; j < 4; ++j) {
      hv += sh_alpha[i * 16 + j * 4 + k] * re_i * sh_te[j * 64 + l];
      tv += sh_alpha[i * 16 + k * 4 + j] * re_i * sh_he[j * 64 + l];
    }
  }
  HVf8[b * NDIM + d] =
      (unsigned char)(__builtin_amdgcn_cvt_pk_fp8_f32(hv, hv, 0, false) & 0xff);
  HVf8[(BATCH + b) * NDIM + d] =
      (unsigned char)(__builtin_amdgcn_cvt_pk_fp8_f32(tv, tv, 0, false) & 0xff);
  float ph = hv * ent_w[h * NDIM + d];
  float pt = tv * ent_w[t * NDIM + d];
  for (int m = 1; m < 64; m <<= 1) { ph += __shfl_xor(ph, m); pt += __shfl_xor(pt, m); }
  int wid = d >> 6;
  if ((d & 63) == 0) { sh_red[wid] = ph; sh_red[8 + wid] = pt; }
  __syncthreads();
  if (d == 0) {
    zlab[b] = sh_red[0] + sh_red[1] + sh_red[2] + sh_red[3];
    zlab[BATCH + b] = sh_red[8] + sh_red[9] + sh_red[10] + sh_red[11];
  }
}

// ---- K3: fp8 MFMA GEMM, A register-resident full-K, B full-K LDS per n-tile,
//          2 barriers/n-tile, LDS power-sum accumulators ----
__global__ void __launch_bounds__(256, 3)
k_gemm(const unsigned char* __restrict__ HVf8, const unsigned char* __restrict__ Wf8,
       float* __restrict__ m1, float* __restrict__ m2) {
  __shared__ __align__(16) unsigned char Bs[BN * NDIM];   // 32 KB fp8, full K
  __shared__ float psm[2][128][17];                       // 17.4 KB, padded buckets
  const int tid = threadIdx.x;
  const int lane = tid & 63, wid = tid >> 6;
  const int L = blockIdx.x;                   // [0, 1024)
  const int xcd = L & 7, rr = L >> 3;         // rr in [0,128)
  const int strip = xcd * 8 + (rr >> 4);      // [0,64): strip's 16 m-blocks share XCD
  const int bm = (rr & 15) * BM;
  const int wm = (wid & 1) * 64, wn = (wid >> 1) * 64;
  const int q = lane >> 4, ln = lane & 15;

  for (int i = tid; i < 2 * 128 * 17; i += 256) ((float*)psm)[i] = 0.f;

  // A fragments resident in registers: 4 mi x 8 k-steps x 8 bytes = 64 VGPR
  long a[4][8];
#pragma unroll
  for (int mi = 0; mi < 4; ++mi) {
    const unsigned char* ap = HVf8 + (bm + wm + mi * 16 + ln) * NDIM + q * 8;
#pragma unroll
    for (int s = 0; s < 8; ++s) a[mi][s] = *(const long*)(ap + s * 32);
  }

  for (int nt = strip; nt < NTILES; nt += NSTRIP) {
    const int bn = nt * BN;
    f32x4 acc[4][4] = {};
    __syncthreads();   // psm zero-init on first pass; Bs reads done on later passes
#pragma unroll
    for (int c = 0; c < 8; ++c) {
      int G = (wid * 8 + c) * 64 + lane;       // granule id [0,2048)
      int row = G >> 4, sr = G & 15;
      int g = (sr & 8) | ((sr & 7) ^ (row & 7));   // XOR swizzle (self-inverse)
      async16(Wf8 + (bn + row) * NDIM + g * 16, (char*)Bs + G * 16);
    }
    __syncthreads();   // drains vmcnt before barrier
#pragma unroll
    for (int st = 0; st < 8; ++st) {
      long bb[4];
      int g = st * 2 + (q >> 1), sub = (q & 1) * 8;
#pragma unroll
      for (int ni = 0; ni < 4; ++ni) {
        int row = wn + ni * 16 + ln;
        int slot = (g & 8) | ((g & 7) ^ (row & 7));
        bb[ni] = *(const long*)(Bs + row * 256 + slot * 16 + sub);
      }
#pragma unroll
      for (int mi = 0; mi < 4; ++mi)
#pragma unroll
        for (int ni = 0; ni < 4; ++ni)
          acc[mi][ni] = __builtin_amdgcn_mfma_f32_16x16x32_fp8_fp8(
              a[mi][st], bb[ni], acc[mi][ni], 0, 0, 0);
    }
    // epilogue: per-row power sums into LDS buckets (64 distinct addrs per op)
#pragma unroll
    for (int mi = 0; mi < 4; ++mi)
#pragma unroll
      for (int reg = 0; reg < 4; ++reg) {
        float s1 = 0.f, s2 = 0.f;
#pragma unroll
        for (int ni = 0; ni < 4; ++ni) {
          float e1 = __expf(acc[mi][ni][reg] * INVBSC - SHIFT);
          s1 += e1; s2 += e1 * e1;
        }
        int row = wm + mi * 16 + q * 4 + reg;   // local row [0,128)
        atomicAdd(&psm[0][row][ln], s1);
        atomicAdd(&psm[1][row][ln], s2);
      }
  }

  __syncthreads();
  // flush: 256 threads = 128 rows x 2 arrays
  int row = tid & 127;
  int arr = tid >> 7;
  float s = 0.f;
#pragma unroll
  for (int c = 0; c < 16; ++c) s += psm[arr][row][c];
  atomicAdd(arr ? &m2[bm + row] : &m1[bm + row], s);
}

// ---- K4: per-row loss assembly + scalar reduce ----
__global__ void k_finalize(const float* __restrict__ m1, const float* __restrict__ m2,
                           const float* __restrict__ zlab, float* __restrict__ out) {
  __shared__ float red[16];
  int tid = threadIdx.x;  // 1024 threads
  float local = 0.f;
  for (int r = tid; r < MROWS; r += 1024) {
    float M1 = m1[r];
    float lse = SHIFT + logf(M1);
    float zl = zlab[r];
    float lp = fmaxf(zl - lse, -100.f);                 // log p_label
    float pl = __expf(zl - lse);
    float l1m = fmaxf(log1pf(-pl), -100.f);             // log(1-p_label)
    float iM1 = 1.f / M1;
    float r2 = m2[r] * iM1 * iM1;
    // sum_e log1p(-p_e) = -(1 + sum p^2/2 + O(p^3)); sum p == 1 exactly
    float series = -(1.f + 0.5f * r2);
    local += lp - l1m + series;
  }
  for (int m = 1; m < 64; m <<= 1) local += __shfl_xor(local, m);
  if ((tid & 63) == 0) red[tid >> 6] = local;
  __syncthreads();
  if (tid == 0) {
    float s = 0.f;
    for (int i = 0; i < 16; ++i) s += red[i];
    out[0] = -s / ((float)BATCH * (float)N_ENT);
  }
}

extern "C" void kernel_launch(void* const* d_in, const int* in_sizes, int n_in,
                              void* d_out, int out_size, void* d_ws, size_t ws_size,
                              hipStream_t stream) {
  const int* facts = (const int*)d_in[0];
  const int* arch = (const int*)d_in[1];
  const float* ent_w = (const float*)d_in[2];
  const float* rel_w = (const float*)d_in[3];
  const float* bne_g = (const float*)d_in[4];
  const float* bne_b = (const float*)d_in[5];
  const float* bnr_g = (const float*)d_in[6];
  const float* bnr_b = (const float*)d_in[7];
  char* ws = (char*)d_ws;
  // layout: [stats 6144][m1 8192][m2 8192][zlab 8192][HVf8 512KB][Wf8 12.8MB]
  float* stats = (float*)ws;
  float* m1 = (float*)(ws + 6144);
  float* m2 = (float*)(ws + 14336);
  float* zlab = (float*)(ws + 22528);
  unsigned char* HVf8 = (unsigned char*)(ws + 30720);
  unsigned char* Wf8 = (unsigned char*)(ws + 30720 + 524288);

  hipMemsetAsync(ws, 0, 22528, stream);  // stats + m1 + m2
  k_prep<<<dim3(NCONV + 192), dim3(256), 0, stream>>>(ent_w, facts, rel_w, Wf8, stats);
  k_vectors<<<dim3(BATCH), dim3(256), 0, stream>>>(facts, arch, ent_w, rel_w,
                                                   bne_g, bne_b, bnr_g, bnr_b,
                                                   stats, HVf8, zlab);
  k_gemm<<<dim3(1024), dim3(256), 0, stream>>>(HVf8, Wf8, m1, m2);
  k_finalize<<<dim3(1), dim3(1024), 0, stream>>>(m1, m2, zlab, (float*)d_out);
}

// Round 4
// 222.742 us; speedup vs baseline: 2.0449x; 2.0449x over previous
//
#include <hip/hip_runtime.h>

#define N_ENT   50000
#define N_ENT_P 50048
#define NDIM    256
#define BATCH   1024
#define MROWS   2048
#define BM      128
#define BN      128
#define NTILES  391
#define NSTRIP  64
#define NBLK    1024
#define NCONV   6256        // N_ENT_P*32/256 convert blocks in k_prep
#define SHIFT   30.0f
#define BSCALE  16.0f
#define INVBSC  0.0625f

typedef __attribute__((ext_vector_type(4))) float f32x4;

__device__ __forceinline__ void async16(const void* g, void* lds) {
  __builtin_amdgcn_global_load_lds(
      (const __attribute__((address_space(1))) unsigned int*)g,
      (__attribute__((address_space(3))) unsigned int*)lds,
      16, 0, 0);
}

// ---- K0: fused [ent_w f32 -> fp8(e4m3, x16) with zero-pad] + [BN stats] ----
__global__ void k_prep(const float* __restrict__ ent_w,
                       const int* __restrict__ facts,
                       const float* __restrict__ rel_w,
                       unsigned char* __restrict__ Wf8,
                       float* __restrict__ stats) {
  int bid = blockIdx.x;
  if (bid < NCONV) {
    int t = bid * 256 + threadIdx.x;          // [0, 50048*32)
    int row = t >> 5, c8 = (t & 31) << 3;
    int2 out;
    if (row < N_ENT) {
      const float4* p = (const float4*)(ent_w + row * NDIM + c8);
      float4 f0 = p[0], f1 = p[1];
      int lo = 0, hi = 0;
      lo = __builtin_amdgcn_cvt_pk_fp8_f32(f0.x * BSCALE, f0.y * BSCALE, lo, false);
      lo = __builtin_amdgcn_cvt_pk_fp8_f32(f0.z * BSCALE, f0.w * BSCALE, lo, true);
      hi = __builtin_amdgcn_cvt_pk_fp8_f32(f1.x * BSCALE, f1.y * BSCALE, hi, false);
      hi = __builtin_amdgcn_cvt_pk_fp8_f32(f1.z * BSCALE, f1.w * BSCALE, hi, true);
      out.x = lo; out.y = hi;
    } else {
      out.x = out.y = 0;
    }
    *(int2*)(Wf8 + row * NDIM + c8) = out;
  } else {
    int sb = bid - NCONV;                      // [0,192)
    int seg = sb >> 6;                         // 0=h, 1=t, 2=r
    int d = threadIdx.x;
    const float* tab = (seg == 2) ? rel_w : ent_w;
    int r0 = (sb & 63) * 16;
    int idxs[16];
#pragma unroll
    for (int i = 0; i < 16; ++i) idxs[i] = facts[(r0 + i) * 3 + seg];
    float s = 0.f, s2 = 0.f;
#pragma unroll
    for (int i = 0; i < 16; ++i) {
      float v = tab[idxs[i] * NDIM + d];
      s += v; s2 += v * v;
    }
    atomicAdd(&stats[(seg * 2 + 0) * NDIM + d], s);
    atomicAdd(&stats[(seg * 2 + 1) * NDIM + d], s2);
  }
}

// ---- K2: BN apply + alpha bilinear -> head/tail vec (fp8) + exact label dots ----
__global__ void k_vectors(const int* __restrict__ facts, const int* __restrict__ arch,
                          const float* __restrict__ ent_w, const float* __restrict__ rel_w,
                          const float* __restrict__ bne_g, const float* __restrict__ bne_b,
                          const float* __restrict__ bnr_g, const float* __restrict__ bnr_b,
                          const float* __restrict__ stats,
                          unsigned char* __restrict__ HVf8, float* __restrict__ zlab) {
  __shared__ float sh_he[256], sh_te[256], sh_re[256], sh_alpha[64], sh_red[16];
  int b = blockIdx.x, d = threadIdx.x;
  int h = facts[b * 3 + 0], t = facts[b * 3 + 1], r = facts[b * 3 + 2];
  const float inv = 1.0f / (float)BATCH;
  float mh = stats[0 * 256 + d] * inv, vh = stats[1 * 256 + d] * inv - mh * mh;
  float mt = stats[2 * 256 + d] * inv, vt = stats[3 * 256 + d] * inv - mt * mt;
  float mr = stats[4 * 256 + d] * inv, vr = stats[5 * 256 + d] * inv - mr * mr;
  float sch = rsqrtf(vh + 1e-5f) * bne_g[d], shh = bne_b[d] - mh * sch;
  float sct = rsqrtf(vt + 1e-5f) * bne_g[d], sht = bne_b[d] - mt * sct;
  float scr = rsqrtf(vr + 1e-5f) * bnr_g[d], shr = bnr_b[d] - mr * scr;
  sh_he[d] = ent_w[h * NDIM + d] * sch + shh;
  sh_te[d] = ent_w[t * NDIM + d] * sct + sht;
  sh_re[d] = rel_w[r * NDIM + d] * scr + shr;
  if (d < 64) {
    int a = arch[d];
    sh_alpha[d] = (a == 0) ? 0.f : ((a == 1) ? 1.f : -1.f);
  }
  __syncthreads();
  int k = d >> 6, l = d & 63;
  float hv = 0.f, tv = 0.f;
#pragma unroll
  for (int i = 0; i < 4; ++i) {
    float re_i = sh_re[i * 64 + l];
#pragma unroll
    for (int j = 0; j < 4; ++j) {
      hv += sh_alpha[i * 16 + j * 4 + k] * re_i * sh_te[j * 64 + l];
      tv += sh_alpha[i * 16 + k * 4 + j] * re_i * sh_he[j * 64 + l];
    }
  }
  HVf8[b * NDIM + d] =
      (unsigned char)(__builtin_amdgcn_cvt_pk_fp8_f32(hv, hv, 0, false) & 0xff);
  HVf8[(BATCH + b) * NDIM + d] =
      (unsigned char)(__builtin_amdgcn_cvt_pk_fp8_f32(tv, tv, 0, false) & 0xff);
  float ph = hv * ent_w[h * NDIM + d];
  float pt = tv * ent_w[t * NDIM + d];
  for (int m = 1; m < 64; m <<= 1) { ph += __shfl_xor(ph, m); pt += __shfl_xor(pt, m); }
  int wid = d >> 6;
  if ((d & 63) == 0) { sh_red[wid] = ph; sh_red[8 + wid] = pt; }
  __syncthreads();
  if (d == 0) {
    zlab[b] = sh_red[0] + sh_red[1] + sh_red[2] + sh_red[3];
    zlab[BATCH + b] = sh_red[8] + sh_red[9] + sh_red[10] + sh_red[11];
  }
}

// ---- K3: fp8 MFMA GEMM; A full-K LDS staged once, B full-K LDS per n-tile;
//          register power sums, one atomic round per block; fused finalize ----
__global__ void __launch_bounds__(256, 2)
k_gemm(const unsigned char* __restrict__ HVf8, const unsigned char* __restrict__ Wf8,
       float* __restrict__ m1, float* __restrict__ m2,
       const float* __restrict__ zlab, int* __restrict__ counter,
       float* __restrict__ out) {
  __shared__ __align__(16) unsigned char As[BM * NDIM];   // 32 KB fp8, full K
  __shared__ __align__(16) unsigned char Bs[BN * NDIM];   // 32 KB fp8, full K
  const int tid = threadIdx.x;
  const int lane = tid & 63, wid = tid >> 6;
  const int L = blockIdx.x;                   // [0, 1024)
  const int xcd = L & 7, rr = L >> 3;         // rr in [0,128)
  const int strip = xcd * 8 + (rr >> 4);      // [0,64): 16 m-blocks share each strip/XCD
  const int bm = (rr & 15) * BM;
  const int wm = (wid & 1) * 64, wn = (wid >> 1) * 64;
  const int q = lane >> 4, ln = lane & 15;

  // stage A once (full K): 2048 granules, XOR-swizzled within each 256B row
#pragma unroll
  for (int c = 0; c < 8; ++c) {
    int G = (wid * 8 + c) * 64 + lane;
    int row = G >> 4, sr = G & 15;
    int g = (sr & 8) | ((sr & 7) ^ (row & 7));
    async16(HVf8 + (bm + row) * NDIM + g * 16, (char*)As + G * 16);
  }

  float ps1[4][4] = {}, ps2[4][4] = {};

  for (int nt = strip; nt < NTILES; nt += NSTRIP) {
    const int bn = nt * BN;
    f32x4 acc[4][4] = {};
    __syncthreads();   // prev iter's Bs reads done
#pragma unroll
    for (int c = 0; c < 8; ++c) {
      int G = (wid * 8 + c) * 64 + lane;
      int row = G >> 4, sr = G & 15;
      int g = (sr & 8) | ((sr & 7) ^ (row & 7));
      async16(Wf8 + (bn + row) * NDIM + g * 16, (char*)Bs + G * 16);
    }
    __syncthreads();   // drains vmcnt (covers A on first pass)
#pragma unroll
    for (int st = 0; st < 8; ++st) {
      long av[4], bv[4];
      int g = st * 2 + (q >> 1), sub = (q & 1) * 8;
#pragma unroll
      for (int mi = 0; mi < 4; ++mi) {
        int row = wm + mi * 16 + ln;
        int slot = (g & 8) | ((g & 7) ^ (row & 7));
        av[mi] = *(const long*)(As + row * 256 + slot * 16 + sub);
      }
#pragma unroll
      for (int ni = 0; ni < 4; ++ni) {
        int row = wn + ni * 16 + ln;
        int slot = (g & 8) | ((g & 7) ^ (row & 7));
        bv[ni] = *(const long*)(Bs + row * 256 + slot * 16 + sub);
      }
#pragma unroll
      for (int mi = 0; mi < 4; ++mi)
#pragma unroll
        for (int ni = 0; ni < 4; ++ni)
          acc[mi][ni] = __builtin_amdgcn_mfma_f32_16x16x32_fp8_fp8(
              av[mi], bv[ni], acc[mi][ni], 0, 0, 0);
    }
    // per-lane register power sums (pad cols contribute e^-30 ~ 0)
#pragma unroll
    for (int mi = 0; mi < 4; ++mi)
#pragma unroll
      for (int reg = 0; reg < 4; ++reg) {
#pragma unroll
        for (int ni = 0; ni < 4; ++ni) {
          float e1 = __expf(acc[mi][ni][reg] * INVBSC - SHIFT);
          ps1[mi][reg] += e1; ps2[mi][reg] += e1 * e1;
        }
      }
  }

  // one shuffle-reduce + atomic round per block
#pragma unroll
  for (int mi = 0; mi < 4; ++mi)
#pragma unroll
    for (int reg = 0; reg < 4; ++reg) {
      float s1 = ps1[mi][reg], s2 = ps2[mi][reg];
      for (int m = 1; m < 16; m <<= 1) { s1 += __shfl_xor(s1, m); s2 += __shfl_xor(s2, m); }
      if (ln == 0) {
        int grow = bm + wm + mi * 16 + q * 4 + reg;
        atomicAdd(&m1[grow], s1);
        atomicAdd(&m2[grow], s2);
      }
    }

  // ---- fused finalize: last block assembles the loss ----
  __threadfence();
  __syncthreads();                 // all lanes' atomics issued & LDS reads done
  volatile int* sh_flag = (volatile int*)Bs;   // reuse LDS
  float* red = (float*)As;
  if (tid == 0) {
    int prev = atomicAdd(counter, 1);
    *sh_flag = (prev == NBLK - 1) ? 1 : 0;
  }
  __syncthreads();
  if (*sh_flag) {
    float local = 0.f;
    for (int r = tid; r < MROWS; r += 256) {
      float M1 = atomicAdd(&m1[r], 0.0f);     // device-coherent read
      float M2 = atomicAdd(&m2[r], 0.0f);
      float lse = SHIFT + logf(M1);
      float zl = zlab[r];
      float lp = fmaxf(zl - lse, -100.f);
      float pl = __expf(zl - lse);
      float l1m = fmaxf(log1pf(-pl), -100.f);
      float iM1 = 1.f / M1;
      float r2 = M2 * iM1 * iM1;
      float series = -(1.f + 0.5f * r2);      // sum_e log1p(-p_e), sum p == 1
      local += lp - l1m + series;
    }
    for (int m = 1; m < 64; m <<= 1) local += __shfl_xor(local, m);
    if (lane == 0) red[wid] = local;
    __syncthreads();
    if (tid == 0)
      out[0] = -(red[0] + red[1] + red[2] + red[3]) / ((float)BATCH * (float)N_ENT);
  }
}

extern "C" void kernel_launch(void* const* d_in, const int* in_sizes, int n_in,
                              void* d_out, int out_size, void* d_ws, size_t ws_size,
                              hipStream_t stream) {
  const int* facts = (const int*)d_in[0];
  const int* arch = (const int*)d_in[1];
  const float* ent_w = (const float*)d_in[2];
  const float* rel_w = (const float*)d_in[3];
  const float* bne_g = (const float*)d_in[4];
  const float* bne_b = (const float*)d_in[5];
  const float* bnr_g = (const float*)d_in[6];
  const float* bnr_b = (const float*)d_in[7];
  char* ws = (char*)d_ws;
  // layout: [stats 6144][m1 8192][m2 8192][zlab 8192][counter 4][pad][HVf8 512KB][Wf8 12.8MB]
  float* stats = (float*)ws;
  float* m1 = (float*)(ws + 6144);
  float* m2 = (float*)(ws + 14336);
  float* zlab = (float*)(ws + 22528);
  int* counter = (int*)(ws + 30720);
  unsigned char* HVf8 = (unsigned char*)(ws + 32768);
  unsigned char* Wf8 = (unsigned char*)(ws + 32768 + 524288);

  hipMemsetAsync(ws, 0, 32768, stream);  // stats + m1 + m2 + counter
  k_prep<<<dim3(NCONV + 192), dim3(256), 0, stream>>>(ent_w, facts, rel_w, Wf8, stats);
  k_vectors<<<dim3(BATCH), dim3(256), 0, stream>>>(facts, arch, ent_w, rel_w,
                                                   bne_g, bne_b, bnr_g, bnr_b,
                                                   stats, HVf8, zlab);
  k_gemm<<<dim3(NBLK), dim3(256), 0, stream>>>(HVf8, Wf8, m1, m2, zlab, counter,
                                               (float*)d_out);
}

// Round 5
// 188.671 us; speedup vs baseline: 2.4141x; 1.1806x over previous
//
#include <hip/hip_runtime.h>

#define N_ENT   50000
#define N_ENT_P 50048
#define NDIM    256
#define BATCH   1024
#define MROWS   2048
#define BM      128
#define BN      128
#define NTILES  391
#define NSTRIP  32
#define NBLK    512
#define NCONV   6256        // N_ENT_P*32/256 convert blocks in k_prep
#define SHIFT   30.0f
#define BSCALE  16.0f
#define INVBSC  0.0625f

typedef __attribute__((ext_vector_type(4))) float f32x4;

__device__ __forceinline__ void async16(const void* g, void* lds) {
  __builtin_amdgcn_global_load_lds(
      (const __attribute__((address_space(1))) unsigned int*)g,
      (__attribute__((address_space(3))) unsigned int*)lds,
      16, 0, 0);
}

// Transposed tile layout: tile t (128 rows), k-granule j in [0,32) (8 bytes of k),
// row r in [0,128):  byte addr = t*32768 + j*1024 + r*8.
// ds_read_b64 at (j,r) hits bank pair 2*(r&15) -> conflict-free fragment reads.

// ---- K0: fused [ent_w f32 -> fp8(e4m3, x16), transposed layout] + [BN stats] ----
__global__ void k_prep(const float* __restrict__ ent_w,
                       const int* __restrict__ facts,
                       const float* __restrict__ rel_w,
                       unsigned char* __restrict__ Wt,
                       float* __restrict__ stats) {
  int bid = blockIdx.x;
  if (bid < NCONV) {
    int t = bid * 256 + threadIdx.x;          // [0, 50048*32)
    int R = t >> 5, c8 = t & 31;              // row, k-granule
    int2 out;
    if (R < N_ENT) {
      const float4* p = (const float4*)(ent_w + R * NDIM + c8 * 8);
      float4 f0 = p[0], f1 = p[1];
      int lo = 0, hi = 0;
      lo = __builtin_amdgcn_cvt_pk_fp8_f32(f0.x * BSCALE, f0.y * BSCALE, lo, false);
      lo = __builtin_amdgcn_cvt_pk_fp8_f32(f0.z * BSCALE, f0.w * BSCALE, lo, true);
      hi = __builtin_amdgcn_cvt_pk_fp8_f32(f1.x * BSCALE, f1.y * BSCALE, hi, false);
      hi = __builtin_amdgcn_cvt_pk_fp8_f32(f1.z * BSCALE, f1.w * BSCALE, hi, true);
      out.x = lo; out.y = hi;
    } else {
      out.x = out.y = 0;
    }
    *(int2*)(Wt + (R >> 7) * 32768 + c8 * 1024 + (R & 127) * 8) = out;
  } else {
    int sb = bid - NCONV;                      // [0,192)
    int seg = sb >> 6;                         // 0=h, 1=t, 2=r
    int d = threadIdx.x;
    const float* tab = (seg == 2) ? rel_w : ent_w;
    int r0 = (sb & 63) * 16;
    int idxs[16];
#pragma unroll
    for (int i = 0; i < 16; ++i) idxs[i] = facts[(r0 + i) * 3 + seg];
    float s = 0.f, s2 = 0.f;
#pragma unroll
    for (int i = 0; i < 16; ++i) {
      float v = tab[idxs[i] * NDIM + d];
      s += v; s2 += v * v;
    }
    atomicAdd(&stats[(seg * 2 + 0) * NDIM + d], s);
    atomicAdd(&stats[(seg * 2 + 1) * NDIM + d], s2);
  }
}

// ---- K2: BN apply + alpha bilinear -> head/tail vec (fp8, transposed) + label dots ----
__global__ void k_vectors(const int* __restrict__ facts, const int* __restrict__ arch,
                          const float* __restrict__ ent_w, const float* __restrict__ rel_w,
                          const float* __restrict__ bne_g, const float* __restrict__ bne_b,
                          const float* __restrict__ bnr_g, const float* __restrict__ bnr_b,
                          const float* __restrict__ stats,
                          unsigned char* __restrict__ HVt, float* __restrict__ zlab) {
  __shared__ float sh_he[256], sh_te[256], sh_re[256], sh_alpha[64], sh_red[16];
  int b = blockIdx.x, d = threadIdx.x;
  int h = facts[b * 3 + 0], t = facts[b * 3 + 1], r = facts[b * 3 + 2];
  const float inv = 1.0f / (float)BATCH;
  float mh = stats[0 * 256 + d] * inv, vh = stats[1 * 256 + d] * inv - mh * mh;
  float mt = stats[2 * 256 + d] * inv, vt = stats[3 * 256 + d] * inv - mt * mt;
  float mr = stats[4 * 256 + d] * inv, vr = stats[5 * 256 + d] * inv - mr * mr;
  float sch = rsqrtf(vh + 1e-5f) * bne_g[d], shh = bne_b[d] - mh * sch;
  float sct = rsqrtf(vt + 1e-5f) * bne_g[d], sht = bne_b[d] - mt * sct;
  float scr = rsqrtf(vr + 1e-5f) * bnr_g[d], shr = bnr_b[d] - mr * scr;
  sh_he[d] = ent_w[h * NDIM + d] * sch + shh;
  sh_te[d] = ent_w[t * NDIM + d] * sct + sht;
  sh_re[d] = rel_w[r * NDIM + d] * scr + shr;
  if (d < 64) {
    int a = arch[d];
    sh_alpha[d] = (a == 0) ? 0.f : ((a == 1) ? 1.f : -1.f);
  }
  __syncthreads();
  int k = d >> 6, l = d & 63;
  float hv = 0.f, tv = 0.f;
#pragma unroll
  for (int i = 0; i < 4; ++i) {
    float re_i = sh_re[i * 64 + l];
#pragma unroll
    for (int j = 0; j < 4; ++j) {
      hv += sh_alpha[i * 16 + j * 4 + k] * re_i * sh_te[j * 64 + l];
      tv += sh_alpha[i * 16 + k * 4 + j] * re_i * sh_he[j * 64 + l];
    }
  }
  // transposed writes: row R, dim d -> (R>>7)*32768 + (d>>3)*1024 + (R&127)*8 + (d&7)
  int R1 = b, R2 = BATCH + b;
  HVt[(R1 >> 7) * 32768 + (d >> 3) * 1024 + (R1 & 127) * 8 + (d & 7)] =
      (unsigned char)(__builtin_amdgcn_cvt_pk_fp8_f32(hv, hv, 0, false) & 0xff);
  HVt[(R2 >> 7) * 32768 + (d >> 3) * 1024 + (R2 & 127) * 8 + (d & 7)] =
      (unsigned char)(__builtin_amdgcn_cvt_pk_fp8_f32(tv, tv, 0, false) & 0xff);
  float ph = hv * ent_w[h * NDIM + d];
  float pt = tv * ent_w[t * NDIM + d];
  for (int m = 1; m < 64; m <<= 1) { ph += __shfl_xor(ph, m); pt += __shfl_xor(pt, m); }
  int wid = d >> 6;
  if ((d & 63) == 0) { sh_red[wid] = ph; sh_red[8 + wid] = pt; }
  __syncthreads();
  if (d == 0) {
    zlab[b] = sh_red[0] + sh_red[1] + sh_red[2] + sh_red[3];
    zlab[BATCH + b] = sh_red[8] + sh_red[9] + sh_red[10] + sh_red[11];
  }
}

// ---- K3: fp8 MFMA GEMM; A in VGPRs (once), B double-buffered LDS;
//          register power sums, one atomic round per block; fused finalize ----
__global__ void __launch_bounds__(256, 2)
k_gemm(const unsigned char* __restrict__ HVt, const unsigned char* __restrict__ Wt,
       float* __restrict__ m1, float* __restrict__ m2,
       const float* __restrict__ zlab, int* __restrict__ counter,
       float* __restrict__ out) {
  __shared__ __align__(16) unsigned char Bs[2][BN * NDIM];   // 2 x 32 KB, transposed
  __shared__ int sh_flag;
  __shared__ float red[4];
  const int tid = threadIdx.x;
  const int lane = tid & 63, wid = tid >> 6;
  const int L = blockIdx.x;                   // [0, 512)
  const int xcd = L & 7, rr = L >> 3;         // rr in [0,64)
  const int strip = xcd * 4 + (rr >> 4);      // [0,32): 16 m-blocks share strip/XCD
  const int mtile = rr & 15;
  const int bm = mtile * BM;
  const int wm = (wid & 1) * 64, wn = (wid >> 1) * 64;
  const int q = lane >> 4, ln = lane & 15;

  // prologue: stage first B tile into buffer 0 (contiguous, no swizzle needed)
  {
    const unsigned char* src = Wt + strip * 32768;
#pragma unroll
    for (int c = 0; c < 8; ++c)
      async16(src + ((wid * 8 + c) * 64 + lane) * 16,
              (char*)Bs[0] + ((wid * 8 + c) * 64 + lane) * 16);
  }

  // A fragments resident: 4 mi x 8 st x 8B = 64 VGPR, coalesced b64 loads
  long av[4][8];
  {
    const unsigned char* Abase = HVt + mtile * 32768;
#pragma unroll
    for (int mi = 0; mi < 4; ++mi)
#pragma unroll
      for (int st = 0; st < 8; ++st)
        av[mi][st] = *(const long*)(Abase + (st * 4 + q) * 1024 + (wm + mi * 16 + ln) * 8);
  }

  float ps1[4][4] = {}, ps2[4][4] = {};
  int pb = 0;

  for (int nt = strip; nt < NTILES; nt += NSTRIP) {
    __syncthreads();   // drains this buffer's staging (issued a full phase ago)
    int nn = nt + NSTRIP;
    if (nn < NTILES) {               // stage next tile into other buffer NOW;
      const unsigned char* src = Wt + nn * 32768;   // flies during compute
#pragma unroll
      for (int c = 0; c < 8; ++c)
        async16(src + ((wid * 8 + c) * 64 + lane) * 16,
                (char*)Bs[pb ^ 1] + ((wid * 8 + c) * 64 + lane) * 16);
    }
    const unsigned char* B0 = Bs[pb];
    f32x4 acc[4][4] = {};
#pragma unroll
    for (int st = 0; st < 8; ++st) {
      long bv[4];
#pragma unroll
      for (int ni = 0; ni < 4; ++ni)
        bv[ni] = *(const long*)(B0 + (st * 4 + q) * 1024 + (wn + ni * 16 + ln) * 8);
#pragma unroll
      for (int mi = 0; mi < 4; ++mi)
#pragma unroll
        for (int ni = 0; ni < 4; ++ni)
          acc[mi][ni] = __builtin_amdgcn_mfma_f32_16x16x32_fp8_fp8(
              av[mi][st], bv[ni], acc[mi][ni], 0, 0, 0);
    }
    // per-lane register power sums (pad cols contribute e^-30 ~ 0)
#pragma unroll
    for (int mi = 0; mi < 4; ++mi)
#pragma unroll
      for (int reg = 0; reg < 4; ++reg) {
#pragma unroll
        for (int ni = 0; ni < 4; ++ni) {
          float e1 = __expf(acc[mi][ni][reg] * INVBSC - SHIFT);
          ps1[mi][reg] += e1; ps2[mi][reg] += e1 * e1;
        }
      }
    pb ^= 1;
  }

  // one shuffle-reduce + atomic round per block
#pragma unroll
  for (int mi = 0; mi < 4; ++mi)
#pragma unroll
    for (int reg = 0; reg < 4; ++reg) {
      float s1 = ps1[mi][reg], s2 = ps2[mi][reg];
      for (int m = 1; m < 16; m <<= 1) { s1 += __shfl_xor(s1, m); s2 += __shfl_xor(s2, m); }
      if (ln == 0) {
        int grow = bm + wm + mi * 16 + q * 4 + reg;
        atomicAdd(&m1[grow], s1);
        atomicAdd(&m2[grow], s2);
      }
    }

  // ---- fused finalize: last block assembles the loss ----
  __threadfence();
  __syncthreads();
  if (tid == 0) {
    int prev = atomicAdd(counter, 1);
    sh_flag = (prev == NBLK - 1) ? 1 : 0;
  }
  __syncthreads();
  if (sh_flag) {
    float local = 0.f;
    for (int r = tid; r < MROWS; r += 256) {
      float M1 = atomicAdd(&m1[r], 0.0f);     // device-coherent read
      float M2 = atomicAdd(&m2[r], 0.0f);
      float lse = SHIFT + logf(M1);
      float zl = zlab[r];
      float lp = fmaxf(zl - lse, -100.f);
      float pl = __expf(zl - lse);
      float l1m = fmaxf(log1pf(-pl), -100.f);
      float iM1 = 1.f / M1;
      float r2 = M2 * iM1 * iM1;
      float series = -(1.f + 0.5f * r2);      // sum_e log1p(-p_e), sum p == 1
      local += lp - l1m + series;
    }
    for (int m = 1; m < 64; m <<= 1) local += __shfl_xor(local, m);
    if (lane == 0) red[wid] = local;
    __syncthreads();
    if (tid == 0)
      out[0] = -(red[0] + red[1] + red[2] + red[3]) / ((float)BATCH * (float)N_ENT);
  }
}

extern "C" void kernel_launch(void* const* d_in, const int* in_sizes, int n_in,
                              void* d_out, int out_size, void* d_ws, size_t ws_size,
                              hipStream_t stream) {
  const int* facts = (const int*)d_in[0];
  const int* arch = (const int*)d_in[1];
  const float* ent_w = (const float*)d_in[2];
  const float* rel_w = (const float*)d_in[3];
  const float* bne_g = (const float*)d_in[4];
  const float* bne_b = (const float*)d_in[5];
  const float* bnr_g = (const float*)d_in[6];
  const float* bnr_b = (const float*)d_in[7];
  char* ws = (char*)d_ws;
  // layout: [stats 6144][m1 8192][m2 8192][zlab 8192][counter..pad to 32768][HVt 512KB][Wt 12.8MB]
  float* stats = (float*)ws;
  float* m1 = (float*)(ws + 6144);
  float* m2 = (float*)(ws + 14336);
  float* zlab = (float*)(ws + 22528);
  int* counter = (int*)(ws + 30720);
  unsigned char* HVt = (unsigned char*)(ws + 32768);
  unsigned char* Wt = (unsigned char*)(ws + 32768 + 524288);

  hipMemsetAsync(ws, 0, 32768, stream);  // stats + m1 + m2 + counter
  k_prep<<<dim3(NCONV + 192), dim3(256), 0, stream>>>(ent_w, facts, rel_w, Wt, stats);
  k_vectors<<<dim3(BATCH), dim3(256), 0, stream>>>(facts, arch, ent_w, rel_w,
                                                   bne_g, bne_b, bnr_g, bnr_b,
                                                   stats, HVt, zlab);
  k_gemm<<<dim3(NBLK), dim3(256), 0, stream>>>(HVt, Wt, m1, m2, zlab, counter,
                                               (float*)d_out);
}

// Round 7
// 180.862 us; speedup vs baseline: 2.5184x; 1.0432x over previous
//
#include <hip/hip_runtime.h>

#define N_ENT   50000
#define N_ENT_P 50048
#define NDIM    256
#define BATCH   1024
#define MROWS   2048
#define BM      128
#define BN      128
#define NTILES  391
#define NSTRIP  32
#define NBLK    512
#define NCONV   6256        // N_ENT_P*32/256 convert blocks in k_prep
#define SHIFT   30.0f
#define BSCALE  16.0f
#define INVBSC  0.0625f

typedef __attribute__((ext_vector_type(4))) float f32x4;

__device__ __forceinline__ void async16(const void* g, void* lds) {
  __builtin_amdgcn_global_load_lds(
      (const __attribute__((address_space(1))) unsigned int*)g,
      (__attribute__((address_space(3))) unsigned int*)lds,
      16, 0, 0);
}

// Transposed tile layout: tile t (128 rows), k-granule j in [0,32) (8 bytes of k),
// row r in [0,128):  byte addr = t*32768 + j*1024 + r*8.
// ds_read_b64 at (j,r) hits bank pair 2*(r&15) -> conflict-free fragment reads.

// ---- K0: fused [ent_w f32 -> fp8(e4m3, x16), transposed layout] + [BN stats] ----
__global__ void k_prep(const float* __restrict__ ent_w,
                       const int* __restrict__ facts,
                       const float* __restrict__ rel_w,
                       unsigned char* __restrict__ Wt,
                       float* __restrict__ stats) {
  int bid = blockIdx.x;
  if (bid < NCONV) {
    int t = bid * 256 + threadIdx.x;          // [0, 50048*32)
    int R = t >> 5, c8 = t & 31;              // row, k-granule
    int2 out;
    if (R < N_ENT) {
      const float4* p = (const float4*)(ent_w + R * NDIM + c8 * 8);
      float4 f0 = p[0], f1 = p[1];
      int lo = 0, hi = 0;
      lo = __builtin_amdgcn_cvt_pk_fp8_f32(f0.x * BSCALE, f0.y * BSCALE, lo, false);
      lo = __builtin_amdgcn_cvt_pk_fp8_f32(f0.z * BSCALE, f0.w * BSCALE, lo, true);
      hi = __builtin_amdgcn_cvt_pk_fp8_f32(f1.x * BSCALE, f1.y * BSCALE, hi, false);
      hi = __builtin_amdgcn_cvt_pk_fp8_f32(f1.z * BSCALE, f1.w * BSCALE, hi, true);
      out.x = lo; out.y = hi;
    } else {
      out.x = out.y = 0;
    }
    *(int2*)(Wt + (R >> 7) * 32768 + c8 * 1024 + (R & 127) * 8) = out;
  } else {
    int sb = bid - NCONV;                      // [0,192)
    int seg = sb >> 6;                         // 0=h, 1=t, 2=r
    int d = threadIdx.x;
    const float* tab = (seg == 2) ? rel_w : ent_w;
    int r0 = (sb & 63) * 16;
    int idxs[16];
#pragma unroll
    for (int i = 0; i < 16; ++i) idxs[i] = facts[(r0 + i) * 3 + seg];
    float s = 0.f, s2 = 0.f;
#pragma unroll
    for (int i = 0; i < 16; ++i) {
      float v = tab[idxs[i] * NDIM + d];
      s += v; s2 += v * v;
    }
    atomicAdd(&stats[(seg * 2 + 0) * NDIM + d], s);
    atomicAdd(&stats[(seg * 2 + 1) * NDIM + d], s2);
  }
}

// ---- K2: BN apply + alpha bilinear -> head/tail vec (fp8, transposed) + label dots ----
__global__ void k_vectors(const int* __restrict__ facts, const int* __restrict__ arch,
                          const float* __restrict__ ent_w, const float* __restrict__ rel_w,
                          const float* __restrict__ bne_g, const float* __restrict__ bne_b,
                          const float* __restrict__ bnr_g, const float* __restrict__ bnr_b,
                          const float* __restrict__ stats,
                          unsigned char* __restrict__ HVt, float* __restrict__ zlab) {
  __shared__ float sh_he[256], sh_te[256], sh_re[256], sh_alpha[64], sh_red[16];
  int b = blockIdx.x, d = threadIdx.x;
  int h = facts[b * 3 + 0], t = facts[b * 3 + 1], r = facts[b * 3 + 2];
  const float inv = 1.0f / (float)BATCH;
  float mh = stats[0 * 256 + d] * inv, vh = stats[1 * 256 + d] * inv - mh * mh;
  float mt = stats[2 * 256 + d] * inv, vt = stats[3 * 256 + d] * inv - mt * mt;
  float mr = stats[4 * 256 + d] * inv, vr = stats[5 * 256 + d] * inv - mr * mr;
  float sch = rsqrtf(vh + 1e-5f) * bne_g[d], shh = bne_b[d] - mh * sch;
  float sct = rsqrtf(vt + 1e-5f) * bne_g[d], sht = bne_b[d] - mt * sct;
  float scr = rsqrtf(vr + 1e-5f) * bnr_g[d], shr = bnr_b[d] - mr * scr;
  sh_he[d] = ent_w[h * NDIM + d] * sch + shh;
  sh_te[d] = ent_w[t * NDIM + d] * sct + sht;
  sh_re[d] = rel_w[r * NDIM + d] * scr + shr;
  if (d < 64) {
    int a = arch[d];
    sh_alpha[d] = (a == 0) ? 0.f : ((a == 1) ? 1.f : -1.f);
  }
  __syncthreads();
  int k = d >> 6, l = d & 63;
  float hv = 0.f, tv = 0.f;
#pragma unroll
  for (int i = 0; i < 4; ++i) {
    float re_i = sh_re[i * 64 + l];
#pragma unroll
    for (int j = 0; j < 4; ++j) {
      hv += sh_alpha[i * 16 + j * 4 + k] * re_i * sh_te[j * 64 + l];
      tv += sh_alpha[i * 16 + k * 4 + j] * re_i * sh_he[j * 64 + l];
    }
  }
  // transposed writes: row R, dim d -> (R>>7)*32768 + (d>>3)*1024 + (R&127)*8 + (d&7)
  int R1 = b, R2 = BATCH + b;
  HVt[(R1 >> 7) * 32768 + (d >> 3) * 1024 + (R1 & 127) * 8 + (d & 7)] =
      (unsigned char)(__builtin_amdgcn_cvt_pk_fp8_f32(hv, hv, 0, false) & 0xff);
  HVt[(R2 >> 7) * 32768 + (d >> 3) * 1024 + (R2 & 127) * 8 + (d & 7)] =
      (unsigned char)(__builtin_amdgcn_cvt_pk_fp8_f32(tv, tv, 0, false) & 0xff);
  float ph = hv * ent_w[h * NDIM + d];
  float pt = tv * ent_w[t * NDIM + d];
  for (int m = 1; m < 64; m <<= 1) { ph += __shfl_xor(ph, m); pt += __shfl_xor(pt, m); }
  int wid = d >> 6;
  if ((d & 63) == 0) { sh_red[wid] = ph; sh_red[8 + wid] = pt; }
  __syncthreads();
  if (d == 0) {
    zlab[b] = sh_red[0] + sh_red[1] + sh_red[2] + sh_red[3];
    zlab[BATCH + b] = sh_red[8] + sh_red[9] + sh_red[10] + sh_red[11];
  }
}

// ---- K3: fp8 MFMA GEMM; A in VGPRs (once), B double-buffered LDS;
//          pipeline order: reads0 -> mfma0 -> reads1 -> prefetch -> mfma1 ----
__global__ void __launch_bounds__(256, 2)
k_gemm(const unsigned char* __restrict__ HVt, const unsigned char* __restrict__ Wt,
       float* __restrict__ m1, float* __restrict__ m2,
       const float* __restrict__ zlab, int* __restrict__ counter,
       float* __restrict__ out) {
  __shared__ __align__(16) unsigned char Bs[2][BN * NDIM];   // 2 x 32 KB, transposed
  __shared__ int sh_flag;
  __shared__ float red[4];
  const int tid = threadIdx.x;
  const int lane = tid & 63, wid = tid >> 6;
  const int L = blockIdx.x;                   // [0, 512)
  const int xcd = L & 7, rr = L >> 3;         // rr in [0,64)
  const int strip = xcd * 4 + (rr >> 4);      // [0,32): 16 m-blocks share strip/XCD
  const int mtile = rr & 15;
  const int bm = mtile * BM;
  const int wm = (wid & 1) * 64, wn = (wid >> 1) * 64;
  const int q = lane >> 4, ln = lane & 15;

  // prologue: stage first B tile into buffer 0 (contiguous, no swizzle needed)
  {
    const unsigned char* src = Wt + strip * 32768;
#pragma unroll
    for (int c = 0; c < 8; ++c) {
      int off = ((wid * 8 + c) * 64 + lane) * 16;
      async16(src + off, (char*)Bs[0] + off);
    }
  }

  // A fragments resident: 4 mi x 8 st x 8B = 64 VGPR, coalesced b64 loads
  long av[4][8];
  {
    const unsigned char* Abase = HVt + mtile * 32768;
#pragma unroll
    for (int mi = 0; mi < 4; ++mi)
#pragma unroll
      for (int st = 0; st < 8; ++st)
        av[mi][st] = *(const long*)(Abase + (st * 4 + q) * 1024 + (wm + mi * 16 + ln) * 8);
  }

  float ps1[4][4] = {}, ps2[4][4] = {};
  int pb = 0;

  for (int nt = strip; nt < NTILES; nt += NSTRIP) {
    __syncthreads();   // drains prefetch issued a full compute-phase ago
    const unsigned char* B0 = Bs[pb];
    int nn = nt + NSTRIP;
    f32x4 acc[4][4] = {};

    // ---- half 0: ds_read st=0..3, then MFMA ----
    long bv0[4][4];
#pragma unroll
    for (int s = 0; s < 4; ++s)
#pragma unroll
      for (int ni = 0; ni < 4; ++ni)
        bv0[s][ni] = *(const long*)(B0 + (s * 4 + q) * 1024 + (wn + ni * 16 + ln) * 8);
#pragma unroll
    for (int s = 0; s < 4; ++s)
#pragma unroll
      for (int mi = 0; mi < 4; ++mi)
#pragma unroll
        for (int ni = 0; ni < 4; ++ni)
          acc[mi][ni] = __builtin_amdgcn_mfma_f32_16x16x32_fp8_fp8(
              av[mi][s], bv0[s][ni], acc[mi][ni], 0, 0, 0);

    // ---- half 1: ds_read st=4..7 FIRST ----
    long bv1[4][4];
#pragma unroll
    for (int s = 0; s < 4; ++s)
#pragma unroll
      for (int ni = 0; ni < 4; ++ni)
        bv1[s][ni] = *(const long*)(B0 + ((s + 4) * 4 + q) * 1024 + (wn + ni * 16 + ln) * 8);

    // ---- THEN issue next-tile prefetch (no ds_read follows until next barrier;
    //      compiler cannot hoist this LDS-store above the may-alias ds_reads) ----
    if (nn < NTILES) {
      const unsigned char* src = Wt + nn * 32768;
      char* dst = (char*)Bs[pb ^ 1];
#pragma unroll
      for (int c = 0; c < 8; ++c) {
        int off = ((wid * 8 + c) * 64 + lane) * 16;
        async16(src + off, dst + off);
      }
    }

    // ---- half 1 MFMA (overlaps prefetch flight) ----
#pragma unroll
    for (int s = 0; s < 4; ++s)
#pragma unroll
      for (int mi = 0; mi < 4; ++mi)
#pragma unroll
        for (int ni = 0; ni < 4; ++ni)
          acc[mi][ni] = __builtin_amdgcn_mfma_f32_16x16x32_fp8_fp8(
              av[mi][s + 4], bv1[s][ni], acc[mi][ni], 0, 0, 0);

    // epilogue: per-lane power sums (pad cols contribute e^-30 ~ 0)
#pragma unroll
    for (int mi = 0; mi < 4; ++mi)
#pragma unroll
      for (int reg = 0; reg < 4; ++reg) {
#pragma unroll
        for (int ni = 0; ni < 4; ++ni) {
          float e1 = __expf(acc[mi][ni][reg] * INVBSC - SHIFT);
          ps1[mi][reg] += e1; ps2[mi][reg] += e1 * e1;
        }
      }
    pb ^= 1;
  }

  // one shuffle-reduce + atomic round per block
#pragma unroll
  for (int mi = 0; mi < 4; ++mi)
#pragma unroll
    for (int reg = 0; reg < 4; ++reg) {
      float s1 = ps1[mi][reg], s2 = ps2[mi][reg];
      for (int m = 1; m < 16; m <<= 1) { s1 += __shfl_xor(s1, m); s2 += __shfl_xor(s2, m); }
      if (ln == 0) {
        int grow = bm + wm + mi * 16 + q * 4 + reg;
        atomicAdd(&m1[grow], s1);
        atomicAdd(&m2[grow], s2);
      }
    }

  // ---- fused finalize: last block assembles the loss ----
  __threadfence();
  __syncthreads();
  if (tid == 0) {
    int prev = atomicAdd(counter, 1);
    sh_flag = (prev == NBLK - 1) ? 1 : 0;
  }
  __syncthreads();
  if (sh_flag) {
    float local = 0.f;
    for (int r = tid; r < MROWS; r += 256) {
      float M1 = atomicAdd(&m1[r], 0.0f);     // device-coherent read
      float M2 = atomicAdd(&m2[r], 0.0f);
      float lse = SHIFT + logf(M1);
      float zl = zlab[r];
      float lp = fmaxf(zl - lse, -100.f);
      float pl = __expf(zl - lse);
      float l1m = fmaxf(log1pf(-pl), -100.f);
      float iM1 = 1.f / M1;
      float r2 = M2 * iM1 * iM1;
      float series = -(1.f + 0.5f * r2);      // sum_e log1p(-p_e); sum p == 1
      local += lp - l1m + series;
    }
    for (int m = 1; m < 64; m <<= 1) local += __shfl_xor(local, m);
    if (lane == 0) red[wid] = local;
    __syncthreads();
    if (tid == 0)
      out[0] = -(red[0] + red[1] + red[2] + red[3]) / ((float)BATCH * (float)N_ENT);
  }
}

extern "C" void kernel_launch(void* const* d_in, const int* in_sizes, int n_in,
                              void* d_out, int out_size, void* d_ws, size_t ws_size,
                              hipStream_t stream) {
  const int* facts = (const int*)d_in[0];
  const int* arch = (const int*)d_in[1];
  const float* ent_w = (const float*)d_in[2];
  const float* rel_w = (const float*)d_in[3];
  const float* bne_g = (const float*)d_in[4];
  const float* bne_b = (const float*)d_in[5];
  const float* bnr_g = (const float*)d_in[6];
  const float* bnr_b = (const float*)d_in[7];
  char* ws = (char*)d_ws;
  // layout: [stats 6144][m1 8192][m2 8192][zlab 8192][counter..pad to 32768][HVt 512KB][Wt 12.8MB]
  float* stats = (float*)ws;
  float* m1 = (float*)(ws + 6144);
  float* m2 = (float*)(ws + 14336);
  float* zlab = (float*)(ws + 22528);
  int* counter = (int*)(ws + 30720);
  unsigned char* HVt = (unsigned char*)(ws + 32768);
  unsigned char* Wt = (unsigned char*)(ws + 32768 + 524288);

  hipMemsetAsync(ws, 0, 32768, stream);  // stats + m1 + m2 + counter
  k_prep<<<dim3(NCONV + 192), dim3(256), 0, stream>>>(ent_w, facts, rel_w, Wt, stats);
  k_vectors<<<dim3(BATCH), dim3(256), 0, stream>>>(facts, arch, ent_w, rel_w,
                                                   bne_g, bne_b, bnr_g, bnr_b,
                                                   stats, HVt, zlab);
  k_gemm<<<dim3(NBLK), dim3(256), 0, stream>>>(HVt, Wt, m1, m2, zlab, counter,
                                               (float*)d_out);
}